// Round 1
// baseline (135.223 us; speedup 1.0000x reference)
//
#include <hip/hip_runtime.h>

// out[b,g] = sum_f x[b, 3g+f] * w[3g+f] + bias[g]
// Flat: i = b*G + g  ->  x offset = 3*i, weight offset = 3*(i % G).
// Memory-bound: 453.6 MB read + 151.2 MB write -> ~96 us floor @ 6.3 TB/s.

#define NUM_GENES 9229
#define TOTAL_OUT (4096 * 9229)   // 37,801,984 — divisible by 4

__global__ __launch_bounds__(256) void diag_layer_kernel(
    const float* __restrict__ x,
    const float* __restrict__ w,
    const float* __restrict__ bias,
    float* __restrict__ out) {

    // Each work-item handles 4 consecutive outputs = 12 consecutive x floats.
    const unsigned n_items = TOTAL_OUT / 4;               // 9,450,496
    unsigned item = blockIdx.x * blockDim.x + threadIdx.x;
    const unsigned stride = gridDim.x * blockDim.x;

    for (; item < n_items; item += stride) {
        const unsigned obase = item * 4u;                 // first output index
        const unsigned xbase = obase * 3u;                // first x element (byte ofs 48*item, 16B aligned)

        const float4 v0 = *reinterpret_cast<const float4*>(x + xbase);
        const float4 v1 = *reinterpret_cast<const float4*>(x + xbase + 4);
        const float4 v2 = *reinterpret_cast<const float4*>(x + xbase + 8);

        const float xe[12] = {v0.x, v0.y, v0.z, v0.w,
                              v1.x, v1.y, v1.z, v1.w,
                              v2.x, v2.y, v2.z, v2.w};

        float r[4];
#pragma unroll
        for (int k = 0; k < 4; ++k) {
            const unsigned i = obase + (unsigned)k;
            const unsigned g = i % NUM_GENES;             // magic-multiply, cheap
            const float* wg = w + 3u * g;
            r[k] = fmaf(xe[3 * k], wg[0],
                   fmaf(xe[3 * k + 1], wg[1],
                   fmaf(xe[3 * k + 2], wg[2], bias[g])));
        }

        *reinterpret_cast<float4*>(out + obase) =
            make_float4(r[0], r[1], r[2], r[3]);
    }
}

extern "C" void kernel_launch(void* const* d_in, const int* in_sizes, int n_in,
                              void* d_out, int out_size, void* d_ws, size_t ws_size,
                              hipStream_t stream) {
    const float* x    = (const float*)d_in[0];
    const float* w    = (const float*)d_in[1];
    const float* bias = (const float*)d_in[2];
    float* out        = (float*)d_out;

    const int block = 256;
    const int grid  = 2048;   // 8 blocks/CU * 256 CUs; grid-stride covers the rest

    diag_layer_kernel<<<grid, block, 0, stream>>>(x, w, bias, out);
}